// Round 1
// 346.376 us; speedup vs baseline: 1.0599x; 1.0599x over previous
//
#include <hip/hip_runtime.h>

#define HID 8
#define OBS_LEN 8
#define PRED_LEN 12
#define SCALE 4.4f
#define BLOCK 256
#define ELEMS_PER_BLOCK 128   // 4 waves * 32 elems per wave

#define LOG2E 1.44269504f
// exp2-arg clamp: tanh tail err ~3e-5 (below baseline absmax 9.8e-4);
// bounds quad-rcp denominator products far away from f32 overflow.
#define ECLAMP 16.0f

typedef __attribute__((ext_vector_type(8)))  _Float16 half8;
typedef __attribute__((ext_vector_type(2)))  _Float16 half2v;
typedef __attribute__((ext_vector_type(16))) float    f32x16;
typedef __attribute__((ext_vector_type(2)))  float    v2f;     // -> v_pk_*_f32

union H8 { half8 v; half2v p[4]; };
struct AB { half8 hi, lo; };

__device__ __forceinline__ v2f splat(float v) { v2f r; r.x = v; r.y = v; return r; }

__device__ __forceinline__ v2f exp2v(v2f a) {
    v2f r;
    r.x = __builtin_amdgcn_exp2f(a.x);
    r.y = __builtin_amdgcn_exp2f(a.y);
    return r;
}

__device__ __forceinline__ half2v pkrtz(float a, float b) {
    return __builtin_bit_cast(half2v, __builtin_amdgcn_cvt_pkrtz(a, b));
}

// fp32 -> f16 hi/lo split, two values per call, packed converts.
// RTZ hi makes |lo| up to 1 ulp(hi); residual a-hi is Sterbenz-exact, so
// hi+lo reconstructs to ~2^-21 rel — same order as the previous RNE split.
__device__ __forceinline__ void split_pair(float a, float b, half2v& hi, half2v& lo) {
    hi = pkrtz(a, b);
    lo = pkrtz(a - (float)hi.x, b - (float)hi.y);
}

// Quad-batched reciprocal: 1 v_rcp + ~5 packed muls for FOUR values.
//   P2 = (d0*d2, d1*d3); r = rcp(P2.x*P2.y)
//   inv0 = (r*d1d3)*d2, inv1 = (r*d0d2)*d3, inv2 = (r*d1d3)*d0, inv3 = (r*d0d2)*d1
// Safe given ECLAMP-bounded factors (see build_A / lstm_pointwise comments).
__device__ __forceinline__ void quad_inv(const v2f d[2], v2f inv[2]) {
    const v2f p2 = d[0] * d[1];
    const float r = __builtin_amdgcn_rcpf(p2.x * p2.y);
    const v2f t = splat(r) * p2;       // (r*d0d2, r*d1d3)
    v2f ts; ts.x = t.y; ts.y = t.x;    // half-swap (op_sel-foldable)
    inv[0] = ts * d[1];
    inv[1] = ts * d[0];
}

// A operand, built once per phase. k-row ordering makes B's per-lane pattern
// IDENTICAL for both half-waves:
//   B rows (half p, lane-local): k=8p+{0..7} = {x0, x1, h[4p+0..4p+3], 1, 0}
//   A rows: p0: {Wih[m][0], Wih[m][1], Whh[m][0..3], bias[m], 0}
//           p1: {0,         0,         Whh[m][4..7], 0,       0}
// NEW: the exp2 prescale is folded into A — i/f/o rows scaled by -log2(e),
// g rows by -2*log2(e) — so the MFMA output feeds v_exp_f32 directly.
__device__ __forceinline__ AB build_A(int m, int half_,
    const float* __restrict__ Wih, const float* __restrict__ Whh,
    const float* __restrict__ bih, const float* __restrict__ bhh)
{
    const float k = ((m >> 3) == 2) ? (-2.0f * LOG2E) : (-LOG2E);
    float w[8];
    if (half_ == 0) {
        w[0] = Wih[m * 2 + 0] * k;
        w[1] = Wih[m * 2 + 1] * k;
        w[2] = Whh[m * 8 + 0] * k;
        w[3] = Whh[m * 8 + 1] * k;
        w[4] = Whh[m * 8 + 2] * k;
        w[5] = Whh[m * 8 + 3] * k;
        w[6] = (bih[m] + bhh[m]) * k;
        w[7] = 0.0f;
    } else {
        w[0] = 0.0f;
        w[1] = 0.0f;
        w[2] = Whh[m * 8 + 4] * k;
        w[3] = Whh[m * 8 + 5] * k;
        w[4] = Whh[m * 8 + 6] * k;
        w[5] = Whh[m * 8 + 7] * k;
        w[6] = 0.0f;
        w[7] = 0.0f;
    }
    H8 hi, lo;
#pragma unroll
    for (int i = 0; i < 4; ++i) split_pair(w[2 * i], w[2 * i + 1], hi.p[i], lo.p[i]);
    AB r; r.hi = hi.v; r.lo = lo.v;
    return r;
}

// B operand: 3 packed splits + constant tail (loop-invariant registers).
__device__ __forceinline__ AB build_B(float x0, float x1, const v2f h[2]) {
    H8 hi, lo;
    split_pair(x0, x1, hi.p[0], lo.p[0]);
    split_pair(h[0].x, h[0].y, hi.p[1], lo.p[1]);
    split_pair(h[1].x, h[1].y, hi.p[2], lo.p[2]);
    const half2v one0 = {(_Float16)1.0f, (_Float16)0.0f};
    const half2v zz   = {(_Float16)0.0f, (_Float16)0.0f};
    hi.p[3] = one0;
    lo.p[3] = zz;
    AB r; r.hi = hi.v; r.lo = lo.v;
    return r;
}

// Pointwise LSTM combine, pair-packed (units {0,1} and {2,3} per lane).
// acc already holds exp2-ready args (scale folded into A):
//   ei = 2^acc_i = e^-preact_i, eg = 2^acc_g = e^-2*preact_g
//   sigma = 1/(1+ei), tanh = (1-eg)/(1+eg)
//   cn = (tg*uf + c*ui*vg) / (uf*ui*vg)   ; h = (1-ec)/(uo*(1+ec))
// Reciprocals quad-batched: 2 v_rcp per step total.
__device__ __forceinline__ void lstm_pointwise(const f32x16& acc, v2f c[2], v2f h[2]) {
    v2f num1[2], den1[2], uo[2];
#pragma unroll
    for (int p = 0; p < 2; ++p) {
        v2f ai, af, agr, ao;
        ai.x  = acc[2 * p + 0];  ai.y  = acc[2 * p + 1];
        af.x  = acc[4 + 2 * p];  af.y  = acc[5 + 2 * p];
        agr.x = acc[8 + 2 * p];  agr.y = acc[9 + 2 * p];
        ao.x  = acc[12 + 2 * p]; ao.y  = acc[13 + 2 * p];
        const v2f ag = __builtin_elementwise_min(agr, splat(ECLAMP));
        const v2f ei = exp2v(ai);
        const v2f ef = exp2v(af);
        const v2f eg = exp2v(ag);
        const v2f eo = exp2v(ao);
        const v2f ui = 1.0f + ei, uf = 1.0f + ef, vg = 1.0f + eg;
        const v2f tg = 1.0f - eg;
        const v2f uiv = ui * vg;
        num1[p] = tg * uf + c[p] * uiv;
        den1[p] = uf * uiv;
        uo[p] = 1.0f + eo;
    }
    v2f inv1[2];
    quad_inv(den1, inv1);

    v2f den2[2], tc[2];
#pragma unroll
    for (int p = 0; p < 2; ++p) {
        const v2f cn = num1[p] * inv1[p];
        c[p] = cn;
        const v2f s = __builtin_elementwise_min(cn * (-2.0f * LOG2E), splat(ECLAMP));
        const v2f ec = exp2v(s);
        den2[p] = uo[p] * (1.0f + ec);
        tc[p] = 1.0f - ec;
    }
    v2f inv2[2];
    quad_inv(den2, inv2);
    h[0] = tc[0] * inv2[0];
    h[1] = tc[1] * inv2[1];
}

// Z is a loop-invariant zero tuple: MFMA reads it as C and writes a fresh D,
// eliminating the 16 v_mov acc-zeroing per step.
__device__ __forceinline__ void lstm_mfma_step(const AB& A, const AB& B, const f32x16& Z,
                                               v2f c[2], v2f h[2]) {
    f32x16 acc = __builtin_amdgcn_mfma_f32_32x32x16_f16(A.hi, B.hi, Z, 0, 0, 0);
    acc = __builtin_amdgcn_mfma_f32_32x32x16_f16(A.hi, B.lo, acc, 0, 0, 0);
    acc = __builtin_amdgcn_mfma_f32_32x32x16_f16(A.lo, B.hi, acc, 0, 0, 0);
    lstm_pointwise(acc, c, h);
}

__global__ __launch_bounds__(BLOCK) void MYLSTM_88201448390683_kernel(
    const float* __restrict__ obs,    // (OBS_LEN, B, 2)
    const float* __restrict__ h0,     // (B, HID)
    const float* __restrict__ c0,     // (B, HID)
    const float* __restrict__ Wih_t, const float* __restrict__ Whh_t,
    const float* __restrict__ bih_t, const float* __restrict__ bhh_t,
    const float* __restrict__ Wih_p, const float* __restrict__ Whh_p,
    const float* __restrict__ bih_p, const float* __restrict__ bhh_p,
    const float* __restrict__ Wp,     // (2, HID)
    const float* __restrict__ bp,     // (2,)
    float* __restrict__ out,          // (PRED_LEN, B, 2)
    int B)
{
    const int lane = threadIdx.x & 63;
    const int wid  = threadIdx.x >> 6;
    const int e    = lane & 31;         // element column; also gate row m for A
    const int half = lane >> 5;

    int eg = blockIdx.x * ELEMS_PER_BLOCK + wid * 32 + e;
    const bool ok = eg < B;
    if (!ok) eg = 0;

    const f32x16 kZero = {};

    // lane owns units 4*half .. 4*half+3 of element eg (C/D layout:
    // row = (reg&3) + 8*(reg>>2) + 4*half => unit=(reg&3)+4*half, gate=reg>>2)
    v2f h[2], c[2];
    {
        const float4 hv = *reinterpret_cast<const float4*>(h0 + (size_t)eg * HID + half * 4);
        const float4 cv = *reinterpret_cast<const float4*>(c0 + (size_t)eg * HID + half * 4);
        h[0].x = hv.x; h[0].y = hv.y; h[1].x = hv.z; h[1].y = hv.w;
        c[0].x = cv.x; c[0].y = cv.y; c[1].x = cv.z; c[1].y = cv.w;
    }

    // ---- encoder ----
    {
        const AB Aenc = build_A(e, half, Wih_t, Whh_t, bih_t, bhh_t);
#pragma unroll 1
        for (int t = 0; t < OBS_LEN; ++t) {
            // both halves load the same element's obs (same address; L1 serves it)
            const v2f xv = *reinterpret_cast<const v2f*>(obs + ((size_t)t * B + eg) * 2);
            const v2f xr = __builtin_elementwise_max(xv, splat(0.0f));
            const AB Bv = build_B(xr.x, xr.y, h);
            lstm_mfma_step(Aenc, Bv, kZero, c, h);
        }
    }

    // ---- decoder ----
    const AB Adec = build_A(e, half, Wih_p, Whh_p, bih_p, bhh_p);
    c[0] = splat(0.0f);
    c[1] = splat(0.0f);

    v2f wa[2], wb[2];
    wa[0].x = Wp[4 * half + 0];       wa[0].y = Wp[4 * half + 1];
    wa[1].x = Wp[4 * half + 2];       wa[1].y = Wp[4 * half + 3];
    wb[0].x = Wp[HID + 4 * half + 0]; wb[0].y = Wp[HID + 4 * half + 1];
    wb[1].x = Wp[HID + 4 * half + 2]; wb[1].y = Wp[HID + 4 * half + 3];
    const float bp0 = bp[0], bp1 = bp[1];

    float x0 = 0.0f, x1 = 0.0f;
#pragma unroll 1
    for (int t = 0; t < PRED_LEN; ++t) {
        const AB Bv = build_B(x0, x1, h);
        lstm_mfma_step(Adec, Bv, kZero, c, h);
        // out = tanh(h @ Wp.T + bp) * SCALE ; h split across lane pairs
        const v2f q0 = wa[0] * h[0] + wa[1] * h[1];
        const v2f q1 = wb[0] * h[0] + wb[1] * h[1];
        float a0 = q0.x + q0.y;
        float a1 = q1.x + q1.y;
        a0 += __shfl_xor(a0, 32);   // both halves now hold the full sums
        a1 += __shfl_xor(a1, 32);
        v2f av; av.x = a0 + bp0; av.y = a1 + bp1;
        // tanh via rational form, one rcp for the pair
        const v2f ev = exp2v(av * (-2.0f * LOG2E));
        const v2f den = 1.0f + ev;
        const float r = __builtin_amdgcn_rcpf(den.x * den.y);
        v2f invv; invv.x = r * den.y; invv.y = r * den.x;
        const v2f xv = (1.0f - ev) * invv * SCALE;
        x0 = xv.x; x1 = xv.y;
        if (!half && ok) {
            *reinterpret_cast<float2*>(out + ((size_t)t * B + eg) * 2) = make_float2(x0, x1);
        }
    }
}

extern "C" void kernel_launch(void* const* d_in, const int* in_sizes, int n_in,
                              void* d_out, int out_size, void* d_ws, size_t ws_size,
                              hipStream_t stream) {
    const float* obs   = (const float*)d_in[0];
    const float* h0    = (const float*)d_in[1];
    const float* c0    = (const float*)d_in[2];
    const float* Wih_t = (const float*)d_in[3];
    const float* Whh_t = (const float*)d_in[4];
    const float* bih_t = (const float*)d_in[5];
    const float* bhh_t = (const float*)d_in[6];
    const float* Wih_p = (const float*)d_in[7];
    const float* Whh_p = (const float*)d_in[8];
    const float* bih_p = (const float*)d_in[9];
    const float* bhh_p = (const float*)d_in[10];
    const float* Wp    = (const float*)d_in[11];
    const float* bp    = (const float*)d_in[12];
    float* out = (float*)d_out;

    const int B = in_sizes[1] / HID;  // h0 is (B, HID)
    const int grid = (B + ELEMS_PER_BLOCK - 1) / ELEMS_PER_BLOCK;

    hipLaunchKernelGGL(MYLSTM_88201448390683_kernel, dim3(grid), dim3(BLOCK), 0, stream,
                       obs, h0, c0,
                       Wih_t, Whh_t, bih_t, bhh_t,
                       Wih_p, Whh_p, bih_p, bhh_p,
                       Wp, bp, out, B);
}

// Round 3
// 343.123 us; speedup vs baseline: 1.0699x; 1.0095x over previous
//
#include <hip/hip_runtime.h>

#define HID 8
#define OBS_LEN 8
#define PRED_LEN 12
#define SCALE 4.4f
#define BLOCK 256
#define ELEMS_PER_BLOCK 128   // 4 waves * 32 elems per wave

#define LOG2E 1.44269504f
// exp2-arg clamp on the cn (cell) path only: |c| can grow ~1/step, so cap the
// exp2 arg at 16 (tanh tail err ~2^-23-ish at arg 16*ln2/2 — far below the
// 2.6e-3 threshold; bounds quad-rcp denominator products << f32 max).
// Gate preacts are structurally bounded (|pre| <= ~12 worst case step-1, h,x
// bounded after) -> den <= 1.6e5, quad product <= 7e20: NO clamp needed there.
#define ECLAMP 16.0f

typedef __attribute__((ext_vector_type(8)))  _Float16 half8;
typedef __attribute__((ext_vector_type(2)))  _Float16 half2v;
typedef __attribute__((ext_vector_type(16))) float    f32x16;
typedef __attribute__((ext_vector_type(2)))  float    v2f;

union H8 { half8 v; half2v p[4]; };
struct AB { half8 hi, lo; };
struct H2 { _Float16 hi, lo; };

__device__ __forceinline__ v2f splat(float v) { v2f r; r.x = v; r.y = v; return r; }

// Packed-f32 discipline (round-2 lesson: NO raw asm — semantics must be
// compiler-verified). <2 x float> fadd/fmul/fma are LEGAL types on gfx90a+
// and select v_pk_{add,mul,fma}_f32 at ISel. __builtin_elementwise_fma emits
// llvm.fma.v2f32 which survives the mid-end as a vector intrinsic; plain
// vector +,-,* on v2f stay vector ops as long as we don't leak per-element
// inserts into the chains. Constant splats (1.0, -1.0) fold to VOP3P inline
// constants (free).
__device__ __forceinline__ v2f vfma(v2f a, v2f b, v2f c) {
    return __builtin_elementwise_fma(a, b, c);
}

__device__ __forceinline__ v2f exp2v(v2f a) {
    v2f r;
    r.x = __builtin_amdgcn_exp2f(a.x);
    r.y = __builtin_amdgcn_exp2f(a.y);
    return r;
}

__device__ __forceinline__ half2v pkrtz(float a, float b) {
    return __builtin_bit_cast(half2v, __builtin_amdgcn_cvt_pkrtz(a, b));
}

// scalar split (build_A only — once per phase, off the hot loop), RNE
__device__ __forceinline__ H2 split1(float v) {
    H2 r;
    r.hi = (_Float16)v;
    r.lo = (_Float16)(v - (float)r.hi);
    return r;
}

// hot-path split: hi = rtz(v); lo = rtz(v - hi). Residual is Sterbenz-exact;
// hi+lo reconstructs to ~2^-21 rel.
__device__ __forceinline__ void split_pair_v(v2f ab, half2v& hi, half2v& lo) {
    hi = pkrtz(ab.x, ab.y);
    v2f hc; hc.x = (float)hi.x; hc.y = (float)hi.y;
    const v2f res = ab - hc;             // vector fsub -> pk_add w/ neg mod
    lo = pkrtz(res.x, res.y);
}

// Quad-batched reciprocal: 1 v_rcp + vector muls for FOUR values.
//   p2 = d0*d1 (elementwise); r = rcp(p2.x*p2.y)
//   t = splat(r)*p2 = (1/p2.y^-1...) ; swap(t) = (1/p2.x, 1/p2.y)
//   inv0 = swap(t)*d1 = 1/d0 ; inv1 = swap(t)*d0 = 1/d1
__device__ __forceinline__ void quad_inv(const v2f d[2], v2f inv[2]) {
    const v2f p2 = d[0] * d[1];
    const float r = __builtin_amdgcn_rcpf(p2.x * p2.y);
    const v2f t = splat(r) * p2;
    v2f ts; ts.x = t.y; ts.y = t.x;
    inv[0] = ts * d[1];
    inv[1] = ts * d[0];
}

// A operand, built once per phase. k-row ordering makes B's per-lane pattern
// IDENTICAL for both half-waves:
//   B rows (half p, lane-local): k=8p+{0..7} = {x0, x1, h[4p+0..4p+3], 1, 0}
//   A rows: p0: {Wih[m][0], Wih[m][1], Whh[m][0..3], bias[m], 0}
//           p1: {0,         0,         Whh[m][4..7], 0,       0}
// exp2 prescale folded into A: i/f/o rows scaled by -log2(e), g rows by
// -2*log2(e), so the MFMA output feeds v_exp_f32 directly.
__device__ __forceinline__ AB build_A(int m, int half_,
    const float* __restrict__ Wih, const float* __restrict__ Whh,
    const float* __restrict__ bih, const float* __restrict__ bhh)
{
    const float k = ((m >> 3) == 2) ? (-2.0f * LOG2E) : (-LOG2E);
    float w[8];
    if (half_ == 0) {
        w[0] = Wih[m * 2 + 0] * k;
        w[1] = Wih[m * 2 + 1] * k;
        w[2] = Whh[m * 8 + 0] * k;
        w[3] = Whh[m * 8 + 1] * k;
        w[4] = Whh[m * 8 + 2] * k;
        w[5] = Whh[m * 8 + 3] * k;
        w[6] = (bih[m] + bhh[m]) * k;
        w[7] = 0.0f;
    } else {
        w[0] = 0.0f;
        w[1] = 0.0f;
        w[2] = Whh[m * 8 + 4] * k;
        w[3] = Whh[m * 8 + 5] * k;
        w[4] = Whh[m * 8 + 6] * k;
        w[5] = Whh[m * 8 + 7] * k;
        w[6] = 0.0f;
        w[7] = 0.0f;
    }
    AB r;
#pragma unroll
    for (int i = 0; i < 8; ++i) {
        const H2 s = split1(w[i]);
        r.hi[i] = s.hi;
        r.lo[i] = s.lo;
    }
    return r;
}

// B operand: 3 packed splits + constant tail.
__device__ __forceinline__ AB build_B(v2f x01, const v2f h[2]) {
    H8 hi, lo;
    split_pair_v(x01, hi.p[0], lo.p[0]);
    split_pair_v(h[0], hi.p[1], lo.p[1]);
    split_pair_v(h[1], hi.p[2], lo.p[2]);
    const half2v one0 = {(_Float16)1.0f, (_Float16)0.0f};
    const half2v zz   = {(_Float16)0.0f, (_Float16)0.0f};
    hi.p[3] = one0;
    lo.p[3] = zz;
    AB r; r.hi = hi.v; r.lo = lo.v;
    return r;
}

// Pointwise LSTM combine, pair-packed (units {0,1} and {2,3} per lane).
// acc holds exp2-ready args (scale folded into A):
//   ei = 2^acc_i = e^-preact_i, eg = 2^acc_g = e^-2*preact_g
//   sigma = 1/(1+ei), tanh = (1-eg)/(1+eg)
//   cn = (tg*uf + c*ui*vg) / (uf*ui*vg)   ; h = (1-ec)/(uo*(1+ec))
// Reciprocals quad-batched: 2 v_rcp per step total.
__device__ __forceinline__ void lstm_pointwise(const f32x16& acc, v2f c[2], v2f h[2]) {
    const v2f vone = splat(1.0f);
    v2f num1[2], den1[2], uo[2];
#pragma unroll
    for (int p = 0; p < 2; ++p) {
        v2f ai, af, ag, ao;
        ai.x = acc[2 * p + 0];  ai.y = acc[2 * p + 1];
        af.x = acc[4 + 2 * p];  af.y = acc[5 + 2 * p];
        ag.x = acc[8 + 2 * p];  ag.y = acc[9 + 2 * p];
        ao.x = acc[12 + 2 * p]; ao.y = acc[13 + 2 * p];
        const v2f ei = exp2v(ai);
        const v2f ef = exp2v(af);
        const v2f eg = exp2v(ag);
        const v2f eo = exp2v(ao);
        const v2f ui = ei + vone;
        const v2f uf = ef + vone;
        const v2f vg = eg + vone;
        const v2f tg = vone - eg;
        const v2f uiv = ui * vg;
        num1[p] = vfma(tg, uf, c[p] * uiv);
        den1[p] = uf * uiv;
        uo[p] = eo + vone;
    }
    v2f inv1[2];
    quad_inv(den1, inv1);

    v2f den2[2], tc[2];
#pragma unroll
    for (int p = 0; p < 2; ++p) {
        const v2f cn = num1[p] * inv1[p];
        c[p] = cn;
        const v2f s0 = cn * splat(-2.0f * LOG2E);
        v2f s; s.x = fminf(s0.x, ECLAMP); s.y = fminf(s0.y, ECLAMP);
        const v2f ec = exp2v(s);
        den2[p] = uo[p] * (ec + vone);
        tc[p] = vone - ec;
    }
    v2f inv2[2];
    quad_inv(den2, inv2);
    h[0] = tc[0] * inv2[0];
    h[1] = tc[1] * inv2[1];
}

// Z is a loop-invariant zero tuple: MFMA reads it as C and writes a fresh D,
// eliminating 16 v_mov acc-zeroing per step.
__device__ __forceinline__ void lstm_mfma_step(const AB& A, const AB& B, const f32x16& Z,
                                               v2f c[2], v2f h[2]) {
    f32x16 acc = __builtin_amdgcn_mfma_f32_32x32x16_f16(A.hi, B.hi, Z, 0, 0, 0);
    acc = __builtin_amdgcn_mfma_f32_32x32x16_f16(A.hi, B.lo, acc, 0, 0, 0);
    acc = __builtin_amdgcn_mfma_f32_32x32x16_f16(A.lo, B.hi, acc, 0, 0, 0);
    lstm_pointwise(acc, c, h);
}

__global__ __launch_bounds__(BLOCK) void MYLSTM_88201448390683_kernel(
    const float* __restrict__ obs,    // (OBS_LEN, B, 2)
    const float* __restrict__ h0,     // (B, HID)
    const float* __restrict__ c0,     // (B, HID)
    const float* __restrict__ Wih_t, const float* __restrict__ Whh_t,
    const float* __restrict__ bih_t, const float* __restrict__ bhh_t,
    const float* __restrict__ Wih_p, const float* __restrict__ Whh_p,
    const float* __restrict__ bih_p, const float* __restrict__ bhh_p,
    const float* __restrict__ Wp,     // (2, HID)
    const float* __restrict__ bp,     // (2,)
    float* __restrict__ out,          // (PRED_LEN, B, 2)
    int B)
{
    const int lane = threadIdx.x & 63;
    const int wid  = threadIdx.x >> 6;
    const int e    = lane & 31;         // element column; also gate row m for A
    const int half = lane >> 5;

    int eg = blockIdx.x * ELEMS_PER_BLOCK + wid * 32 + e;
    const bool ok = eg < B;
    if (!ok) eg = 0;

    const f32x16 kZero = {};

    // lane owns units 4*half .. 4*half+3 of element eg (C/D layout:
    // row = (reg&3) + 8*(reg>>2) + 4*half => unit=(reg&3)+4*half, gate=reg>>2)
    v2f h[2], c[2];
    {
        const float4 hv = *reinterpret_cast<const float4*>(h0 + (size_t)eg * HID + half * 4);
        const float4 cv = *reinterpret_cast<const float4*>(c0 + (size_t)eg * HID + half * 4);
        h[0].x = hv.x; h[0].y = hv.y; h[1].x = hv.z; h[1].y = hv.w;
        c[0].x = cv.x; c[0].y = cv.y; c[1].x = cv.z; c[1].y = cv.w;
    }

    // ---- encoder ----
    {
        const AB Aenc = build_A(e, half, Wih_t, Whh_t, bih_t, bhh_t);
        const float* op = obs + (size_t)eg * 2;
        const size_t ostride = (size_t)B * 2;
#pragma unroll 1
        for (int t = 0; t < OBS_LEN; ++t) {
            // both halves load the same element's obs (same address; L1 serves it)
            const v2f xv = *reinterpret_cast<const v2f*>(op);
            op += ostride;
            v2f xr; xr.x = fmaxf(xv.x, 0.0f); xr.y = fmaxf(xv.y, 0.0f);
            const AB Bv = build_B(xr, h);
            lstm_mfma_step(Aenc, Bv, kZero, c, h);
        }
    }

    // ---- decoder ----
    const AB Adec = build_A(e, half, Wih_p, Whh_p, bih_p, bhh_p);
    c[0] = splat(0.0f);
    c[1] = splat(0.0f);

    v2f wa[2], wb[2];
    wa[0].x = Wp[4 * half + 0];       wa[0].y = Wp[4 * half + 1];
    wa[1].x = Wp[4 * half + 2];       wa[1].y = Wp[4 * half + 3];
    wb[0].x = Wp[HID + 4 * half + 0]; wb[0].y = Wp[HID + 4 * half + 1];
    wb[1].x = Wp[HID + 4 * half + 2]; wb[1].y = Wp[HID + 4 * half + 3];
    const float bp0 = bp[0], bp1 = bp[1];

    v2f x01 = splat(0.0f);
#pragma unroll 1
    for (int t = 0; t < PRED_LEN; ++t) {
        const AB Bv = build_B(x01, h);
        lstm_mfma_step(Adec, Bv, kZero, c, h);
        // out = tanh(h @ Wp.T + bp) * SCALE ; h split across lane pairs
        const v2f q0 = vfma(wa[1], h[1], wa[0] * h[0]);
        const v2f q1 = vfma(wb[1], h[1], wb[0] * h[0]);
        float a0 = q0.x + q0.y;
        float a1 = q1.x + q1.y;
        a0 += __shfl_xor(a0, 32);   // both halves now hold the full sums
        a1 += __shfl_xor(a1, 32);
        v2f av; av.x = a0 + bp0; av.y = a1 + bp1;
        // tanh via rational form, one rcp for the pair
        const v2f ev = exp2v(av * splat(-2.0f * LOG2E));
        const v2f den = ev + splat(1.0f);
        const float r = __builtin_amdgcn_rcpf(den.x * den.y);
        v2f ds; ds.x = den.y; ds.y = den.x;
        const v2f invv = splat(r) * ds;
        const v2f tn = splat(1.0f) - ev;
        x01 = (tn * invv) * splat(SCALE);
        if (!half && ok) {
            *reinterpret_cast<float2*>(out + ((size_t)t * B + eg) * 2) = make_float2(x01.x, x01.y);
        }
    }
}

extern "C" void kernel_launch(void* const* d_in, const int* in_sizes, int n_in,
                              void* d_out, int out_size, void* d_ws, size_t ws_size,
                              hipStream_t stream) {
    const float* obs   = (const float*)d_in[0];
    const float* h0    = (const float*)d_in[1];
    const float* c0    = (const float*)d_in[2];
    const float* Wih_t = (const float*)d_in[3];
    const float* Whh_t = (const float*)d_in[4];
    const float* bih_t = (const float*)d_in[5];
    const float* bhh_t = (const float*)d_in[6];
    const float* Wih_p = (const float*)d_in[7];
    const float* Whh_p = (const float*)d_in[8];
    const float* bih_p = (const float*)d_in[9];
    const float* bhh_p = (const float*)d_in[10];
    const float* Wp    = (const float*)d_in[11];
    const float* bp    = (const float*)d_in[12];
    float* out = (float*)d_out;

    const int B = in_sizes[1] / HID;  // h0 is (B, HID)
    const int grid = (B + ELEMS_PER_BLOCK - 1) / ELEMS_PER_BLOCK;

    hipLaunchKernelGGL(MYLSTM_88201448390683_kernel, dim3(grid), dim3(BLOCK), 0, stream,
                       obs, h0, c0,
                       Wih_t, Whh_t, bih_t, bhh_t,
                       Wih_p, Whh_p, bih_p, bhh_p,
                       Wp, bp, out, B);
}